// Round 1
// baseline (585.272 us; speedup 1.0000x reference)
//
#include <hip/hip_runtime.h>
#include <math.h>

// FNO2d: B=4, C=3, H=W=256, L=4, WIDTH=32, M1=M2=12
// Spectral conv done as truncated DFTs (only 24 kx x 12 ky modes survive).
//
// ws layout (floats):
//   cs  [512]      : cos/sin(2*pi*p/256), p=0..255
//   Fy  [6144]     : interleaved cos/sin for e^{-2pi i ky y/256}, ky=0..11, y=0..255
//   h   [8388608]  : activations (B,32,H,W), updated in place per layer
//   tmp [786432]   : stage-A output (B,32,H,12) complex; ALIASED with g (stage-C out)
//   hf  [73728]    : (B,32,24,12) complex
//   am  [73728]    : (B,32,24,12) complex (after channel mix)

#define ANG0 0.024543692606170260f  // 2*pi/256

__global__ void k_init(float* __restrict__ cs, float* __restrict__ Fy) {
    int p = threadIdx.x;
    cs[p]       = cosf(p * ANG0);
    cs[256 + p] = sinf(p * ANG0);
    for (int ky = 0; ky < 12; ++ky) {
        int q = (ky * p) & 255;
        Fy[(ky * 256 + p) * 2]     = cosf(q * ANG0);
        Fy[(ky * 256 + p) * 2 + 1] = sinf(q * ANG0);
    }
}

__global__ __launch_bounds__(256) void k_lift(const float* __restrict__ xin,
                                              const float* __restrict__ pw,
                                              const float* __restrict__ pb,
                                              float* __restrict__ h) {
    int b = blockIdx.x >> 8, x = blockIdx.x & 255, y = threadIdx.x;
    float f0 = xin[((b * 3 + 0) * 256 + x) * 256 + y];
    float f1 = xin[((b * 3 + 1) * 256 + x) * 256 + y];
    float f2 = xin[((b * 3 + 2) * 256 + x) * 256 + y];
    float gx = x * (1.0f / 255.0f), gy = y * (1.0f / 255.0f);
#pragma unroll
    for (int o = 0; o < 32; ++o) {
        float v = pb[o] + f0 * pw[o] + f1 * pw[32 + o] + f2 * pw[64 + o]
                + gx * pw[96 + o] + gy * pw[128 + o];
        h[((b * 32 + o) * 256 + x) * 256 + y] = v;
    }
}

// Stage A: tmp[b,i,x,ky] = sum_y h[b,i,x,y] * e^{-2pi i ky y/256}, ky=0..11
__global__ __launch_bounds__(64) void k_dfty(const float* __restrict__ h,
                                             const float* __restrict__ Fy,
                                             float* __restrict__ tmp) {
    int row = blockIdx.x;            // (b*32+i)*256 + x
    int lane = threadIdx.x;
    float4 hv = reinterpret_cast<const float4*>(h + (size_t)row * 256)[lane];
    float aR[12], aI[12];
#pragma unroll
    for (int ky = 0; ky < 12; ++ky) {
        const float4* fp = reinterpret_cast<const float4*>(Fy + (ky * 256 + lane * 4) * 2);
        float4 f0 = fp[0], f1 = fp[1];  // (c0,s0,c1,s1),(c2,s2,c3,s3)
        aR[ky] = hv.x * f0.x + hv.y * f0.z + hv.z * f1.x + hv.w * f1.z;
        aI[ky] = -(hv.x * f0.y + hv.y * f0.w + hv.z * f1.y + hv.w * f1.w);
    }
#pragma unroll
    for (int off = 32; off; off >>= 1) {
#pragma unroll
        for (int ky = 0; ky < 12; ++ky) {
            aR[ky] += __shfl_xor(aR[ky], off);
            aI[ky] += __shfl_xor(aI[ky], off);
        }
    }
    if (lane == 0) {
        float* tp = tmp + (size_t)row * 24;
#pragma unroll
        for (int ky = 0; ky < 12; ++ky) { tp[2 * ky] = aR[ky]; tp[2 * ky + 1] = aI[ky]; }
    }
}

// Stage B: hf[b,i,kxi,ky] = sum_x tmp[b,i,x,ky] * e^{-2pi i kxv x/256}
__global__ __launch_bounds__(320) void k_dftx(const float* __restrict__ tmp,
                                              const float* __restrict__ cs,
                                              float* __restrict__ hf) {
    __shared__ float sT[6144];
    __shared__ float sCS[512];
    int plane = blockIdx.x;          // b*32+i
    int tid = threadIdx.x;
    for (int idx = tid; idx < 6144; idx += 320) sT[idx] = tmp[(size_t)plane * 6144 + idx];
    for (int idx = tid; idx < 512; idx += 320) sCS[idx] = cs[idx];
    __syncthreads();
    if (tid < 288) {
        int kxi = tid / 12, ky = tid % 12;
        int kxv = kxi < 12 ? kxi : 232 + kxi;  // 244..255
        float aR = 0.f, aI = 0.f;
        for (int x = 0; x < 256; ++x) {
            int p = (kxv * x) & 255;
            float c = sCS[p], s = sCS[256 + p];
            float tr = sT[x * 24 + 2 * ky], ti = sT[x * 24 + 2 * ky + 1];
            aR += tr * c + ti * s;     // (tr + i ti) * (c - i s)
            aI += ti * c - tr * s;
        }
        hf[((size_t)plane * 24 + kxi) * 24 + 2 * ky]     = aR;
        hf[((size_t)plane * 24 + kxi) * 24 + 2 * ky + 1] = aI;
    }
}

// Mode mix: am[b,o,kxi,ky] = sum_i hf[b,i,kxi,ky] * w[i,o,rk,ky]  (complex)
__global__ __launch_bounds__(384) void k_mix(const float* __restrict__ hf,
                                             const float* __restrict__ w1r,
                                             const float* __restrict__ w1i,
                                             const float* __restrict__ w2r,
                                             const float* __restrict__ w2i,
                                             float* __restrict__ am, int l) {
    __shared__ float sHF[768];
    int b = blockIdx.x / 24, kxi = blockIdx.x % 24;
    int tid = threadIdx.x;
    for (int idx = tid; idx < 768; idx += 384) {
        int i = idx / 24, rem = idx % 24;
        sHF[idx] = hf[(((size_t)b * 32 + i) * 24 + kxi) * 24 + rem];
    }
    __syncthreads();
    int o = tid / 12, ky = tid % 12;
    const float *wr, *wi;
    int rk;
    if (kxi < 12) { wr = w1r; wi = w1i; rk = kxi; }
    else          { wr = w2r; wi = w2i; rk = kxi - 12; }
    size_t base = (size_t)l * 1024 * 144 + rk * 12 + ky;
    float aR = 0.f, aI = 0.f;
#pragma unroll 8
    for (int i = 0; i < 32; ++i) {
        float hr = sHF[i * 24 + 2 * ky], hi = sHF[i * 24 + 2 * ky + 1];
        float wrv = wr[base + (size_t)(i * 32 + o) * 144];
        float wiv = wi[base + (size_t)(i * 32 + o) * 144];
        aR += hr * wrv - hi * wiv;
        aI += hr * wiv + hi * wrv;
    }
    am[(((size_t)b * 32 + o) * 24 + kxi) * 24 + 2 * ky]     = aR;
    am[(((size_t)b * 32 + o) * 24 + kxi) * 24 + 2 * ky + 1] = aI;
}

// Stage C: g[b,o,x,ky] = sum_kx am[b,o,kx,ky] * e^{+2pi i kxv x/256}
__global__ __launch_bounds__(256) void k_cinv(const float* __restrict__ am,
                                              const float* __restrict__ cs,
                                              float* __restrict__ g) {
    __shared__ float sA[576];
    __shared__ float sCS[512];
    int plane = blockIdx.x;          // b*32+o
    int tid = threadIdx.x;
    for (int idx = tid; idx < 576; idx += 256) sA[idx] = am[(size_t)plane * 576 + idx];
    for (int idx = tid; idx < 512; idx += 256) sCS[idx] = cs[idx];
    __syncthreads();
    int x = tid;
    float out[24];
#pragma unroll
    for (int j = 0; j < 24; ++j) out[j] = 0.f;
    for (int kxi = 0; kxi < 24; ++kxi) {
        int kxv = kxi < 12 ? kxi : 232 + kxi;
        int p = (kxv * x) & 255;
        float c = sCS[p], s = sCS[256 + p];
#pragma unroll
        for (int ky = 0; ky < 12; ++ky) {
            float ar = sA[kxi * 24 + 2 * ky], ai = sA[kxi * 24 + 2 * ky + 1];
            out[2 * ky]     += ar * c - ai * s;
            out[2 * ky + 1] += ar * s + ai * c;
        }
    }
    float* gp = g + (size_t)plane * 6144 + x * 24;
#pragma unroll
    for (int j = 0; j < 24; ++j) gp[j] = out[j];
}

// Stage D: h[b,o,x,y] = act( spectral/65536 + bypass + cb )   (in place)
__global__ __launch_bounds__(256) void k_dinv(float* __restrict__ h,
                                              const float* __restrict__ g,
                                              const float* __restrict__ cw,
                                              const float* __restrict__ cb,
                                              const float* __restrict__ cs,
                                              int l, int act) {
    __shared__ float sH[32 * 256];
    __shared__ float sG[32 * 24];
    __shared__ float sCWT[32 * 36];   // [o][i], padded stride 36
    __shared__ float sCB[32];
    __shared__ float sCS[512];
    int b = blockIdx.x >> 8, x = blockIdx.x & 255;
    int y = threadIdx.x;
#pragma unroll
    for (int i = 0; i < 32; ++i) sH[i * 256 + y] = h[(((size_t)b * 32 + i) * 256 + x) * 256 + y];
    for (int idx = y; idx < 768; idx += 256) {
        int o = idx / 24, r = idx % 24;
        sG[idx] = g[(((size_t)b * 32 + o) * 256 + x) * 24 + r];
    }
    for (int idx = y; idx < 1024; idx += 256) {
        int i = idx >> 5, o = idx & 31;
        sCWT[o * 36 + i] = cw[l * 1024 + idx];
    }
    if (y < 32) sCB[y] = cb[l * 32 + y];
    for (int idx = y; idx < 512; idx += 256) sCS[idx] = cs[idx];
    __syncthreads();
    float hreg[32];
#pragma unroll
    for (int i = 0; i < 32; ++i) hreg[i] = sH[i * 256 + y];
    float ck[12], sk[12];
#pragma unroll
    for (int ky = 1; ky < 12; ++ky) {
        int p = (ky * y) & 255;
        ck[ky] = sCS[p]; sk[ky] = sCS[256 + p];
    }
#pragma unroll 4
    for (int o = 0; o < 32; ++o) {
        float spec = sG[o * 24];   // Re(g[ky=0]); Im of DC bin ignored by irfft
#pragma unroll
        for (int ky = 1; ky < 12; ++ky)
            spec += 2.0f * (sG[o * 24 + 2 * ky] * ck[ky] - sG[o * 24 + 2 * ky + 1] * sk[ky]);
        float v = spec * (1.0f / 65536.0f) + sCB[o];
#pragma unroll
        for (int i4 = 0; i4 < 8; ++i4) {
            float4 w4 = *reinterpret_cast<const float4*>(&sCWT[o * 36 + i4 * 4]);
            v += hreg[i4 * 4] * w4.x + hreg[i4 * 4 + 1] * w4.y
               + hreg[i4 * 4 + 2] * w4.z + hreg[i4 * 4 + 3] * w4.w;
        }
        if (act) v = 0.5f * v * (1.0f + erff(v * 0.70710678118f));
        h[(((size_t)b * 32 + o) * 256 + x) * 256 + y] = v;
    }
}

__global__ __launch_bounds__(256) void k_mlp(const float* __restrict__ h,
                                             const float* __restrict__ w0,
                                             const float* __restrict__ b0,
                                             const float* __restrict__ w1,
                                             const float* __restrict__ b1,
                                             float* __restrict__ out) {
    __shared__ float sH[32 * 256];
    __shared__ float sW0[128 * 36];   // [k][i], padded stride 36
    __shared__ float sB0[128];
    __shared__ float sW1[384];
    __shared__ float sB1[4];
    int b = blockIdx.x >> 8, x = blockIdx.x & 255;
    int y = threadIdx.x;
#pragma unroll
    for (int i = 0; i < 32; ++i) sH[i * 256 + y] = h[(((size_t)b * 32 + i) * 256 + x) * 256 + y];
    for (int idx = y; idx < 4096; idx += 256) {
        int i = idx >> 7, k = idx & 127;
        sW0[k * 36 + i] = w0[idx];
    }
    if (y < 128) sB0[y] = b0[y];
    for (int idx = y; idx < 384; idx += 256) sW1[idx] = w1[idx];
    if (y < 3) sB1[y] = b1[y];
    __syncthreads();
    float hreg[32];
#pragma unroll
    for (int i = 0; i < 32; ++i) hreg[i] = sH[i * 256 + y];
    float o0 = sB1[0], o1 = sB1[1], o2 = sB1[2];
    for (int k = 0; k < 128; ++k) {
        float t = sB0[k];
#pragma unroll
        for (int i4 = 0; i4 < 8; ++i4) {
            float4 w4 = *reinterpret_cast<const float4*>(&sW0[k * 36 + i4 * 4]);
            t += hreg[i4 * 4] * w4.x + hreg[i4 * 4 + 1] * w4.y
               + hreg[i4 * 4 + 2] * w4.z + hreg[i4 * 4 + 3] * w4.w;
        }
        t = 0.5f * t * (1.0f + erff(t * 0.70710678118f));
        o0 += t * sW1[k * 3];
        o1 += t * sW1[k * 3 + 1];
        o2 += t * sW1[k * 3 + 2];
    }
    out[(((size_t)b * 3 + 0) * 256 + x) * 256 + y] = o0;
    out[(((size_t)b * 3 + 1) * 256 + x) * 256 + y] = o1;
    out[(((size_t)b * 3 + 2) * 256 + x) * 256 + y] = o2;
}

extern "C" void kernel_launch(void* const* d_in, const int* in_sizes, int n_in,
                              void* d_out, int out_size, void* d_ws, size_t ws_size,
                              hipStream_t stream) {
    const float* xin  = (const float*)d_in[0];
    const float* pw   = (const float*)d_in[1];
    const float* pb   = (const float*)d_in[2];
    const float* sw1r = (const float*)d_in[3];
    const float* sw1i = (const float*)d_in[4];
    const float* sw2r = (const float*)d_in[5];
    const float* sw2i = (const float*)d_in[6];
    const float* cw   = (const float*)d_in[7];
    const float* cb   = (const float*)d_in[8];
    const float* w0   = (const float*)d_in[9];
    const float* b0   = (const float*)d_in[10];
    const float* w1   = (const float*)d_in[11];
    const float* b1   = (const float*)d_in[12];
    float* out = (float*)d_out;

    float* ws  = (float*)d_ws;
    float* cs  = ws;                  // 512
    float* Fy  = cs + 512;            // 6144
    float* h   = Fy + 6144;           // 8388608
    float* tmp = h + 8388608;         // 786432 (aliased with g)
    float* hf  = tmp + 786432;        // 73728
    float* am  = hf + 73728;          // 73728
    float* g   = tmp;                 // alias: tmp is dead after k_dftx

    k_init<<<1, 256, 0, stream>>>(cs, Fy);
    k_lift<<<1024, 256, 0, stream>>>(xin, pw, pb, h);
    for (int l = 0; l < 4; ++l) {
        k_dfty<<<32768, 64, 0, stream>>>(h, Fy, tmp);
        k_dftx<<<128, 320, 0, stream>>>(tmp, cs, hf);
        k_mix<<<96, 384, 0, stream>>>(hf, sw1r, sw1i, sw2r, sw2i, am, l);
        k_cinv<<<128, 256, 0, stream>>>(am, cs, g);
        k_dinv<<<1024, 256, 0, stream>>>(h, g, cw, cb, cs, l, (l < 3) ? 1 : 0);
    }
    k_mlp<<<1024, 256, 0, stream>>>(h, w0, b0, w1, b1, out);
}

// Round 2
// 556.446 us; speedup vs baseline: 1.0518x; 1.0518x over previous
//
#include <hip/hip_runtime.h>
#include <math.h>

// FNO2d: B=4, C=3, H=W=256, L=4, WIDTH=32, M1=M2=12
// Truncated-DFT spectral conv. This round: 4-pixel register blocking for the
// two VALU-heavy kernels (k_dinv, k_mlp), branchless erf, dftx 4-way split.
//
// ws layout (floats):
//   cs  [512]      : cos/sin(2*pi*p/256)
//   Fy  [6144]     : interleaved cos/sin for ky-forward DFT
//   h   [8388608]  : activations (B,32,H,W), in place per layer
//   tmp [786432]   : stage-A out (B,32,H,12) complex; ALIASED with g
//   hfp [294912]   : 4 x-partials of (B,32,24,12) complex
//   am  [73728]    : (B,32,24,12) complex after channel mix

#define ANG0 0.024543692606170260f  // 2*pi/256

__device__ __forceinline__ float fgelu(float v) {
    // exact-GELU via A&S 7.1.26 erf approx, |err| <= 1.5e-7, branchless
    float u = v * 0.70710678118f;
    float a = fabsf(u);
    float t = __builtin_amdgcn_rcpf(__builtin_fmaf(0.3275911f, a, 1.0f));
    float p = t * __builtin_fmaf(t, __builtin_fmaf(t, __builtin_fmaf(t,
                  __builtin_fmaf(t, 1.061405429f, -1.453152027f),
                  1.421413741f), -0.284496736f), 0.254829592f);
    float e = __expf(-u * u);
    float er = __builtin_fmaf(-p, e, 1.0f);
    er = copysignf(er, u);
    return 0.5f * v * (1.0f + er);
}

__global__ void k_init(float* __restrict__ cs, float* __restrict__ Fy) {
    int p = threadIdx.x;
    cs[p]       = cosf(p * ANG0);
    cs[256 + p] = sinf(p * ANG0);
    for (int ky = 0; ky < 12; ++ky) {
        int q = (ky * p) & 255;
        Fy[(ky * 256 + p) * 2]     = cosf(q * ANG0);
        Fy[(ky * 256 + p) * 2 + 1] = sinf(q * ANG0);
    }
}

__global__ __launch_bounds__(256) void k_lift(const float* __restrict__ xin,
                                              const float* __restrict__ pw,
                                              const float* __restrict__ pb,
                                              float* __restrict__ h) {
    int b = blockIdx.x >> 8, x = blockIdx.x & 255, y = threadIdx.x;
    float f0 = xin[((b * 3 + 0) * 256 + x) * 256 + y];
    float f1 = xin[((b * 3 + 1) * 256 + x) * 256 + y];
    float f2 = xin[((b * 3 + 2) * 256 + x) * 256 + y];
    float gx = x * (1.0f / 255.0f), gy = y * (1.0f / 255.0f);
#pragma unroll
    for (int o = 0; o < 32; ++o) {
        float v = pb[o] + f0 * pw[o] + f1 * pw[32 + o] + f2 * pw[64 + o]
                + gx * pw[96 + o] + gy * pw[128 + o];
        h[((b * 32 + o) * 256 + x) * 256 + y] = v;
    }
}

// Stage A: tmp[b,i,x,ky] = sum_y h[b,i,x,y] * e^{-2pi i ky y/256}
__global__ __launch_bounds__(64) void k_dfty(const float* __restrict__ h,
                                             const float* __restrict__ Fy,
                                             float* __restrict__ tmp) {
    int row = blockIdx.x;
    int lane = threadIdx.x;
    float4 hv = reinterpret_cast<const float4*>(h + (size_t)row * 256)[lane];
    float aR[12], aI[12];
#pragma unroll
    for (int ky = 0; ky < 12; ++ky) {
        const float4* fp = reinterpret_cast<const float4*>(Fy + (ky * 256 + lane * 4) * 2);
        float4 f0 = fp[0], f1 = fp[1];
        aR[ky] = hv.x * f0.x + hv.y * f0.z + hv.z * f1.x + hv.w * f1.z;
        aI[ky] = -(hv.x * f0.y + hv.y * f0.w + hv.z * f1.y + hv.w * f1.w);
    }
#pragma unroll
    for (int off = 32; off; off >>= 1) {
#pragma unroll
        for (int ky = 0; ky < 12; ++ky) {
            aR[ky] += __shfl_xor(aR[ky], off);
            aI[ky] += __shfl_xor(aI[ky], off);
        }
    }
    if (lane == 0) {
        float* tp = tmp + (size_t)row * 24;
#pragma unroll
        for (int ky = 0; ky < 12; ++ky) { tp[2 * ky] = aR[ky]; tp[2 * ky + 1] = aI[ky]; }
    }
}

// Stage B (4-way x-split): hfp[part][plane][kxi][ky] partial over 64 x's
__global__ __launch_bounds__(320) void k_dftx(const float* __restrict__ tmp,
                                              const float* __restrict__ cs,
                                              float* __restrict__ hfp) {
    __shared__ float sT[1536];     // 64 x * 24
    __shared__ float sCS[512];
    int plane = blockIdx.x >> 2, part = blockIdx.x & 3;
    int x0 = part * 64;
    int tid = threadIdx.x;
    for (int idx = tid; idx < 1536; idx += 320)
        sT[idx] = tmp[(size_t)plane * 6144 + x0 * 24 + idx];
    for (int idx = tid; idx < 512; idx += 320) sCS[idx] = cs[idx];
    __syncthreads();
    if (tid < 288) {
        int kxi = tid / 12, ky = tid % 12;
        int kxv = kxi < 12 ? kxi : 232 + kxi;
        float aR = 0.f, aI = 0.f;
        for (int xp = 0; xp < 64; ++xp) {
            int p = (kxv * (x0 + xp)) & 255;
            float c = sCS[p], s = sCS[256 + p];
            float tr = sT[xp * 24 + 2 * ky], ti = sT[xp * 24 + 2 * ky + 1];
            aR += tr * c + ti * s;
            aI += ti * c - tr * s;
        }
        hfp[(((size_t)part * 128 + plane) * 24 + kxi) * 24 + 2 * ky]     = aR;
        hfp[(((size_t)part * 128 + plane) * 24 + kxi) * 24 + 2 * ky + 1] = aI;
    }
}

// Mode mix (sums the 4 dftx partials while staging)
__global__ __launch_bounds__(384) void k_mix(const float* __restrict__ hfp,
                                             const float* __restrict__ w1r,
                                             const float* __restrict__ w1i,
                                             const float* __restrict__ w2r,
                                             const float* __restrict__ w2i,
                                             float* __restrict__ am, int l) {
    __shared__ float sHF[768];
    int b = blockIdx.x / 24, kxi = blockIdx.x % 24;
    int tid = threadIdx.x;
    for (int idx = tid; idx < 768; idx += 384) {
        int i = idx / 24, rem = idx % 24;
        size_t base = (((size_t)(b * 32 + i)) * 24 + kxi) * 24 + rem;
        sHF[idx] = hfp[base] + hfp[128 * 576 + base] + hfp[2 * 128 * 576 + base]
                 + hfp[3 * 128 * 576 + base];
    }
    __syncthreads();
    int o = tid / 12, ky = tid % 12;
    const float *wr, *wi;
    int rk;
    if (kxi < 12) { wr = w1r; wi = w1i; rk = kxi; }
    else          { wr = w2r; wi = w2i; rk = kxi - 12; }
    size_t base = (size_t)l * 1024 * 144 + rk * 12 + ky;
    float aR = 0.f, aI = 0.f;
#pragma unroll 8
    for (int i = 0; i < 32; ++i) {
        float hr = sHF[i * 24 + 2 * ky], hi = sHF[i * 24 + 2 * ky + 1];
        float wrv = wr[base + (size_t)(i * 32 + o) * 144];
        float wiv = wi[base + (size_t)(i * 32 + o) * 144];
        aR += hr * wrv - hi * wiv;
        aI += hr * wiv + hi * wrv;
    }
    am[(((size_t)b * 32 + o) * 24 + kxi) * 24 + 2 * ky]     = aR;
    am[(((size_t)b * 32 + o) * 24 + kxi) * 24 + 2 * ky + 1] = aI;
}

// Stage C: g[b,o,x,ky] = sum_kx am[b,o,kx,ky] * e^{+2pi i kxv x/256}
__global__ __launch_bounds__(256) void k_cinv(const float* __restrict__ am,
                                              const float* __restrict__ cs,
                                              float* __restrict__ g) {
    __shared__ float sA[576];
    __shared__ float sCS[512];
    int plane = blockIdx.x;
    int tid = threadIdx.x;
    for (int idx = tid; idx < 576; idx += 256) sA[idx] = am[(size_t)plane * 576 + idx];
    for (int idx = tid; idx < 512; idx += 256) sCS[idx] = cs[idx];
    __syncthreads();
    int x = tid;
    float out[24];
#pragma unroll
    for (int j = 0; j < 24; ++j) out[j] = 0.f;
    for (int kxi = 0; kxi < 24; ++kxi) {
        int kxv = kxi < 12 ? kxi : 232 + kxi;
        int p = (kxv * x) & 255;
        float c = sCS[p], s = sCS[256 + p];
#pragma unroll
        for (int ky = 0; ky < 12; ++ky) {
            float ar = sA[kxi * 24 + 2 * ky], ai = sA[kxi * 24 + 2 * ky + 1];
            out[2 * ky]     += ar * c - ai * s;
            out[2 * ky + 1] += ar * s + ai * c;
        }
    }
    float* gp = g + (size_t)plane * 6144 + x * 24;
#pragma unroll
    for (int j = 0; j < 24; ++j) gp[j] = out[j];
}

// Stage D: 4 rows per block, 4 pixels per thread (same y, rows X..X+3)
__global__ __launch_bounds__(256) void k_dinv(float* __restrict__ h,
                                              const float* __restrict__ g,
                                              const float* __restrict__ cw,
                                              const float* __restrict__ cb,
                                              const float* __restrict__ cs,
                                              int l, int act) {
    __shared__ float sG[3072];     // [r][o][j]
    __shared__ float sW[1024];     // [o][i] broadcast
    __shared__ float sCB[32];
    __shared__ float sCS[512];
    int b = blockIdx.x >> 6, X = (blockIdx.x & 63) * 4;
    int y = threadIdx.x;
    for (int idx = y; idx < 3072; idx += 256) {
        int r = idx / 768, rem = idx - r * 768;
        int o = rem / 24, j = rem - o * 24;
        sG[idx] = g[(((size_t)(b * 32 + o)) * 256 + X + r) * 24 + j];
    }
    for (int idx = y; idx < 1024; idx += 256) {
        int i = idx >> 5, o = idx & 31;
        sW[o * 32 + i] = cw[l * 1024 + idx];
    }
    if (y < 32) sCB[y] = cb[l * 32 + y];
    for (int idx = y; idx < 512; idx += 256) sCS[idx] = cs[idx];
    float hreg[4][32];
#pragma unroll
    for (int r = 0; r < 4; ++r)
#pragma unroll
        for (int i = 0; i < 32; ++i)
            hreg[r][i] = h[(((size_t)(b * 32 + i)) * 256 + X + r) * 256 + y];
    __syncthreads();
    float ck[12], sk[12];
#pragma unroll
    for (int ky = 1; ky < 12; ++ky) {
        int p = (ky * y) & 255;
        ck[ky] = 2.0f * sCS[p]; sk[ky] = 2.0f * sCS[256 + p];
    }
    for (int o = 0; o < 32; ++o) {
        float v[4];
#pragma unroll
        for (int r = 0; r < 4; ++r) {
            const float4* gp = reinterpret_cast<const float4*>(sG + r * 768 + o * 24);
            float4 g0 = gp[0], g1 = gp[1], g2 = gp[2], g3 = gp[3], g4 = gp[4], g5 = gp[5];
            float spec = g0.x
                + (g0.z * ck[1] - g0.w * sk[1]) + (g1.x * ck[2] - g1.y * sk[2])
                + (g1.z * ck[3] - g1.w * sk[3]) + (g2.x * ck[4] - g2.y * sk[4])
                + (g2.z * ck[5] - g2.w * sk[5]) + (g3.x * ck[6] - g3.y * sk[6])
                + (g3.z * ck[7] - g3.w * sk[7]) + (g4.x * ck[8] - g4.y * sk[8])
                + (g4.z * ck[9] - g4.w * sk[9]) + (g5.x * ck[10] - g5.y * sk[10])
                + (g5.z * ck[11] - g5.w * sk[11]);
            v[r] = spec * (1.0f / 65536.0f) + sCB[o];
        }
#pragma unroll
        for (int i4 = 0; i4 < 8; ++i4) {
            float4 w4 = *reinterpret_cast<const float4*>(sW + o * 32 + i4 * 4);
#pragma unroll
            for (int r = 0; r < 4; ++r)
                v[r] += hreg[r][i4 * 4] * w4.x + hreg[r][i4 * 4 + 1] * w4.y
                      + hreg[r][i4 * 4 + 2] * w4.z + hreg[r][i4 * 4 + 3] * w4.w;
        }
#pragma unroll
        for (int r = 0; r < 4; ++r) {
            float vv = act ? fgelu(v[r]) : v[r];
            h[(((size_t)(b * 32 + o)) * 256 + X + r) * 256 + y] = vv;
        }
    }
}

// Final MLP: 4 rows per block, 4 pixels per thread
__global__ __launch_bounds__(256) void k_mlp(const float* __restrict__ h,
                                             const float* __restrict__ w0,
                                             const float* __restrict__ b0,
                                             const float* __restrict__ w1,
                                             const float* __restrict__ b1,
                                             float* __restrict__ out) {
    __shared__ float sW0[4096];    // [k][i] broadcast
    __shared__ float sB0[128];
    __shared__ float sW1[384];
    __shared__ float sB1[4];
    int b = blockIdx.x >> 6, X = (blockIdx.x & 63) * 4;
    int y = threadIdx.x;
    for (int idx = y; idx < 4096; idx += 256) {
        int k = idx >> 5, i = idx & 31;
        sW0[idx] = w0[i * 128 + k];
    }
    if (y < 128) sB0[y] = b0[y];
    for (int idx = y; idx < 384; idx += 256) sW1[idx] = w1[idx];
    if (y < 4) sB1[y] = (y < 3) ? b1[y] : 0.f;
    float hreg[4][32];
#pragma unroll
    for (int r = 0; r < 4; ++r)
#pragma unroll
        for (int i = 0; i < 32; ++i)
            hreg[r][i] = h[(((size_t)(b * 32 + i)) * 256 + X + r) * 256 + y];
    __syncthreads();
    float a0[4], a1[4], a2[4];
#pragma unroll
    for (int r = 0; r < 4; ++r) { a0[r] = sB1[0]; a1[r] = sB1[1]; a2[r] = sB1[2]; }
    for (int k = 0; k < 128; ++k) {
        float t[4];
        float bk = sB0[k];
#pragma unroll
        for (int r = 0; r < 4; ++r) t[r] = bk;
#pragma unroll
        for (int i4 = 0; i4 < 8; ++i4) {
            float4 w4 = *reinterpret_cast<const float4*>(sW0 + k * 32 + i4 * 4);
#pragma unroll
            for (int r = 0; r < 4; ++r)
                t[r] += hreg[r][i4 * 4] * w4.x + hreg[r][i4 * 4 + 1] * w4.y
                      + hreg[r][i4 * 4 + 2] * w4.z + hreg[r][i4 * 4 + 3] * w4.w;
        }
        float wa = sW1[k * 3], wb = sW1[k * 3 + 1], wc = sW1[k * 3 + 2];
#pragma unroll
        for (int r = 0; r < 4; ++r) {
            float tg = fgelu(t[r]);
            a0[r] += tg * wa; a1[r] += tg * wb; a2[r] += tg * wc;
        }
    }
#pragma unroll
    for (int r = 0; r < 4; ++r) {
        out[(((size_t)b * 3 + 0) * 256 + X + r) * 256 + y] = a0[r];
        out[(((size_t)b * 3 + 1) * 256 + X + r) * 256 + y] = a1[r];
        out[(((size_t)b * 3 + 2) * 256 + X + r) * 256 + y] = a2[r];
    }
}

extern "C" void kernel_launch(void* const* d_in, const int* in_sizes, int n_in,
                              void* d_out, int out_size, void* d_ws, size_t ws_size,
                              hipStream_t stream) {
    const float* xin  = (const float*)d_in[0];
    const float* pw   = (const float*)d_in[1];
    const float* pb   = (const float*)d_in[2];
    const float* sw1r = (const float*)d_in[3];
    const float* sw1i = (const float*)d_in[4];
    const float* sw2r = (const float*)d_in[5];
    const float* sw2i = (const float*)d_in[6];
    const float* cw   = (const float*)d_in[7];
    const float* cb   = (const float*)d_in[8];
    const float* w0   = (const float*)d_in[9];
    const float* b0   = (const float*)d_in[10];
    const float* w1   = (const float*)d_in[11];
    const float* b1   = (const float*)d_in[12];
    float* out = (float*)d_out;

    float* ws  = (float*)d_ws;
    float* cs  = ws;                  // 512
    float* Fy  = cs + 512;            // 6144
    float* h   = Fy + 6144;           // 8388608
    float* tmp = h + 8388608;         // 786432 (aliased with g)
    float* hfp = tmp + 786432;        // 294912 (4 partials)
    float* am  = hfp + 294912;        // 73728
    float* g   = tmp;                 // alias: tmp dead after k_dftx

    k_init<<<1, 256, 0, stream>>>(cs, Fy);
    k_lift<<<1024, 256, 0, stream>>>(xin, pw, pb, h);
    for (int l = 0; l < 4; ++l) {
        k_dfty<<<32768, 64, 0, stream>>>(h, Fy, tmp);
        k_dftx<<<512, 320, 0, stream>>>(tmp, cs, hfp);
        k_mix<<<96, 384, 0, stream>>>(hfp, sw1r, sw1i, sw2r, sw2i, am, l);
        k_cinv<<<128, 256, 0, stream>>>(am, cs, g);
        k_dinv<<<256, 256, 0, stream>>>(h, g, cw, cb, cs, l, (l < 3) ? 1 : 0);
    }
    k_mlp<<<256, 256, 0, stream>>>(h, w0, b0, w1, b1, out);
}

// Round 3
// 414.391 us; speedup vs baseline: 1.4124x; 1.3428x over previous
//
#include <hip/hip_runtime.h>
#include <math.h>

// FNO2d: B=4, C=3, H=W=256, L=4, WIDTH=32, M1=M2=12
// Truncated-DFT spectral conv. R3: 2px/thread (occupancy fix), shuffle-free
// register-rotation k_dfty, Fy table dropped.
//
// ws layout (floats):
//   cs  [512]      : cos/sin(2*pi*p/256)
//   h   [8388608]  : activations (B,32,H,W), in place per layer
//   tmp [786432]   : stage-A out (B,32,H,12) complex; ALIASED with g
//   hfp [294912]   : 4 x-partials of (B,32,24,12) complex
//   am  [73728]    : (B,32,24,12) complex after channel mix

#define ANG0 0.024543692606170260f  // 2*pi/256

__device__ __forceinline__ float fgelu(float v) {
    // exact-GELU via A&S 7.1.26 erf approx, |err| <= 1.5e-7, branchless
    float u = v * 0.70710678118f;
    float a = fabsf(u);
    float t = __builtin_amdgcn_rcpf(__builtin_fmaf(0.3275911f, a, 1.0f));
    float p = t * __builtin_fmaf(t, __builtin_fmaf(t, __builtin_fmaf(t,
                  __builtin_fmaf(t, 1.061405429f, -1.453152027f),
                  1.421413741f), -0.284496736f), 0.254829592f);
    float e = __expf(-u * u);
    float er = __builtin_fmaf(-p, e, 1.0f);
    er = copysignf(er, u);
    return 0.5f * v * (1.0f + er);
}

__global__ void k_init(float* __restrict__ cs) {
    int p = threadIdx.x;
    cs[p]       = cosf(p * ANG0);
    cs[256 + p] = sinf(p * ANG0);
}

__global__ __launch_bounds__(256) void k_lift(const float* __restrict__ xin,
                                              const float* __restrict__ pw,
                                              const float* __restrict__ pb,
                                              float* __restrict__ h) {
    int b = blockIdx.x >> 8, x = blockIdx.x & 255, y = threadIdx.x;
    float f0 = xin[((b * 3 + 0) * 256 + x) * 256 + y];
    float f1 = xin[((b * 3 + 1) * 256 + x) * 256 + y];
    float f2 = xin[((b * 3 + 2) * 256 + x) * 256 + y];
    float gx = x * (1.0f / 255.0f), gy = y * (1.0f / 255.0f);
#pragma unroll
    for (int o = 0; o < 32; ++o) {
        float v = pb[o] + f0 * pw[o] + f1 * pw[32 + o] + f2 * pw[64 + o]
                + gx * pw[96 + o] + gy * pw[128 + o];
        h[((b * 32 + o) * 256 + x) * 256 + y] = v;
    }
}

// Stage A: tmp[row, ky] = sum_y h[row, y] * e^{-2pi i ky y/256}
// 32 rows/block, one thread per (row, ky) complex output, phase by rotation.
__global__ __launch_bounds__(384) void k_dfty(const float* __restrict__ h,
                                              float* __restrict__ tmp) {
    __shared__ float sH[32 * 260];   // stride 260: (4r+y)%32 distinct, 16B-aligned
    int tid = threadIdx.x;
    for (int idx = tid; idx < 2048; idx += 384) {
        int r = idx >> 6, yq = idx & 63;
        float4 v = reinterpret_cast<const float4*>(h + ((size_t)blockIdx.x * 32 + r) * 256)[yq];
        *reinterpret_cast<float4*>(&sH[r * 260 + yq * 4]) = v;
    }
    __syncthreads();
    int r = tid / 12, ky = tid % 12;
    float cst = cosf(ky * ANG0), sst = sinf(ky * ANG0);
    float c = 1.f, s = 0.f, aR = 0.f, aI = 0.f;
    const float* hp = sH + r * 260;
#pragma unroll 8
    for (int y = 0; y < 256; ++y) {
        float hv = hp[y];
        aR = __builtin_fmaf(hv, c, aR);
        aI = __builtin_fmaf(hv, s, aI);
        float cn = __builtin_fmaf(c, cst, s * sst);
        s = __builtin_fmaf(s, cst, -c * sst);
        c = cn;
    }
    float2 res = make_float2(aR, aI);
    reinterpret_cast<float2*>(tmp + ((size_t)blockIdx.x * 32 + r) * 24)[ky] = res;
}

// Stage B (4-way x-split): hfp[part][plane][kxi][ky] partial over 64 x's
__global__ __launch_bounds__(320) void k_dftx(const float* __restrict__ tmp,
                                              const float* __restrict__ cs,
                                              float* __restrict__ hfp) {
    __shared__ float sT[1536];     // 64 x * 24
    __shared__ float sCS[512];
    int plane = blockIdx.x >> 2, part = blockIdx.x & 3;
    int x0 = part * 64;
    int tid = threadIdx.x;
    for (int idx = tid; idx < 1536; idx += 320)
        sT[idx] = tmp[(size_t)plane * 6144 + x0 * 24 + idx];
    for (int idx = tid; idx < 512; idx += 320) sCS[idx] = cs[idx];
    __syncthreads();
    if (tid < 288) {
        int kxi = tid / 12, ky = tid % 12;
        int kxv = kxi < 12 ? kxi : 232 + kxi;
        float aR = 0.f, aI = 0.f;
        for (int xp = 0; xp < 64; ++xp) {
            int p = (kxv * (x0 + xp)) & 255;
            float c = sCS[p], s = sCS[256 + p];
            float tr = sT[xp * 24 + 2 * ky], ti = sT[xp * 24 + 2 * ky + 1];
            aR += tr * c + ti * s;
            aI += ti * c - tr * s;
        }
        hfp[(((size_t)part * 128 + plane) * 24 + kxi) * 24 + 2 * ky]     = aR;
        hfp[(((size_t)part * 128 + plane) * 24 + kxi) * 24 + 2 * ky + 1] = aI;
    }
}

// Mode mix (sums the 4 dftx partials while staging)
__global__ __launch_bounds__(384) void k_mix(const float* __restrict__ hfp,
                                             const float* __restrict__ w1r,
                                             const float* __restrict__ w1i,
                                             const float* __restrict__ w2r,
                                             const float* __restrict__ w2i,
                                             float* __restrict__ am, int l) {
    __shared__ float sHF[768];
    int b = blockIdx.x / 24, kxi = blockIdx.x % 24;
    int tid = threadIdx.x;
    for (int idx = tid; idx < 768; idx += 384) {
        int i = idx / 24, rem = idx % 24;
        size_t base = (((size_t)(b * 32 + i)) * 24 + kxi) * 24 + rem;
        sHF[idx] = hfp[base] + hfp[128 * 576 + base] + hfp[2 * 128 * 576 + base]
                 + hfp[3 * 128 * 576 + base];
    }
    __syncthreads();
    int o = tid / 12, ky = tid % 12;
    const float *wr, *wi;
    int rk;
    if (kxi < 12) { wr = w1r; wi = w1i; rk = kxi; }
    else          { wr = w2r; wi = w2i; rk = kxi - 12; }
    size_t base = (size_t)l * 1024 * 144 + rk * 12 + ky;
    float aR = 0.f, aI = 0.f;
#pragma unroll 8
    for (int i = 0; i < 32; ++i) {
        float hr = sHF[i * 24 + 2 * ky], hi = sHF[i * 24 + 2 * ky + 1];
        float wrv = wr[base + (size_t)(i * 32 + o) * 144];
        float wiv = wi[base + (size_t)(i * 32 + o) * 144];
        aR += hr * wrv - hi * wiv;
        aI += hr * wiv + hi * wrv;
    }
    am[(((size_t)b * 32 + o) * 24 + kxi) * 24 + 2 * ky]     = aR;
    am[(((size_t)b * 32 + o) * 24 + kxi) * 24 + 2 * ky + 1] = aI;
}

// Stage C: g[b,o,x,ky] = sum_kx am[b,o,kx,ky] * e^{+2pi i kxv x/256}
__global__ __launch_bounds__(256) void k_cinv(const float* __restrict__ am,
                                              const float* __restrict__ cs,
                                              float* __restrict__ g) {
    __shared__ float sA[576];
    __shared__ float sCS[512];
    int plane = blockIdx.x;
    int tid = threadIdx.x;
    for (int idx = tid; idx < 576; idx += 256) sA[idx] = am[(size_t)plane * 576 + idx];
    for (int idx = tid; idx < 512; idx += 256) sCS[idx] = cs[idx];
    __syncthreads();
    int x = tid;
    float out[24];
#pragma unroll
    for (int j = 0; j < 24; ++j) out[j] = 0.f;
    for (int kxi = 0; kxi < 24; ++kxi) {
        int kxv = kxi < 12 ? kxi : 232 + kxi;
        int p = (kxv * x) & 255;
        float c = sCS[p], s = sCS[256 + p];
#pragma unroll
        for (int ky = 0; ky < 12; ++ky) {
            float ar = sA[kxi * 24 + 2 * ky], ai = sA[kxi * 24 + 2 * ky + 1];
            out[2 * ky]     += ar * c - ai * s;
            out[2 * ky + 1] += ar * s + ai * c;
        }
    }
    float* gp = g + (size_t)plane * 6144 + x * 24;
#pragma unroll
    for (int j = 0; j < 24; ++j) gp[j] = out[j];
}

// Stage D: 2 rows per block, 2 pixels per thread (same y, rows X..X+1)
__global__ __launch_bounds__(256) void k_dinv(float* __restrict__ h,
                                              const float* __restrict__ g,
                                              const float* __restrict__ cw,
                                              const float* __restrict__ cb,
                                              const float* __restrict__ cs,
                                              int l, int act) {
    __shared__ float sG[1536];     // [r][o][j]
    __shared__ float sW[1024];     // [o][i] broadcast
    __shared__ float sCB[32];
    __shared__ float sCS[512];
    int b = blockIdx.x >> 7, X = (blockIdx.x & 127) * 2;
    int y = threadIdx.x;
    for (int idx = y; idx < 1536; idx += 256) {
        int r = idx / 768, rem = idx - r * 768;
        int o = rem / 24, j = rem - o * 24;
        sG[idx] = g[(((size_t)(b * 32 + o)) * 256 + X + r) * 24 + j];
    }
    for (int idx = y; idx < 1024; idx += 256) {
        int i = idx >> 5, o = idx & 31;
        sW[o * 32 + i] = cw[l * 1024 + idx];
    }
    if (y < 32) sCB[y] = cb[l * 32 + y];
    for (int idx = y; idx < 512; idx += 256) sCS[idx] = cs[idx];
    float hreg[2][32];
#pragma unroll
    for (int r = 0; r < 2; ++r)
#pragma unroll
        for (int i = 0; i < 32; ++i)
            hreg[r][i] = h[(((size_t)(b * 32 + i)) * 256 + X + r) * 256 + y];
    __syncthreads();
    float ck[12], sk[12];
#pragma unroll
    for (int ky = 1; ky < 12; ++ky) {
        int p = (ky * y) & 255;
        ck[ky] = 2.0f * sCS[p]; sk[ky] = 2.0f * sCS[256 + p];
    }
    for (int o = 0; o < 32; ++o) {
        float v[2];
#pragma unroll
        for (int r = 0; r < 2; ++r) {
            const float4* gp = reinterpret_cast<const float4*>(sG + r * 768 + o * 24);
            float4 g0 = gp[0], g1 = gp[1], g2 = gp[2], g3 = gp[3], g4 = gp[4], g5 = gp[5];
            float spec = g0.x
                + (g0.z * ck[1] - g0.w * sk[1]) + (g1.x * ck[2] - g1.y * sk[2])
                + (g1.z * ck[3] - g1.w * sk[3]) + (g2.x * ck[4] - g2.y * sk[4])
                + (g2.z * ck[5] - g2.w * sk[5]) + (g3.x * ck[6] - g3.y * sk[6])
                + (g3.z * ck[7] - g3.w * sk[7]) + (g4.x * ck[8] - g4.y * sk[8])
                + (g4.z * ck[9] - g4.w * sk[9]) + (g5.x * ck[10] - g5.y * sk[10])
                + (g5.z * ck[11] - g5.w * sk[11]);
            v[r] = spec * (1.0f / 65536.0f) + sCB[o];
        }
#pragma unroll
        for (int i4 = 0; i4 < 8; ++i4) {
            float4 w4 = *reinterpret_cast<const float4*>(sW + o * 32 + i4 * 4);
#pragma unroll
            for (int r = 0; r < 2; ++r)
                v[r] += hreg[r][i4 * 4] * w4.x + hreg[r][i4 * 4 + 1] * w4.y
                      + hreg[r][i4 * 4 + 2] * w4.z + hreg[r][i4 * 4 + 3] * w4.w;
        }
#pragma unroll
        for (int r = 0; r < 2; ++r) {
            float vv = act ? fgelu(v[r]) : v[r];
            h[(((size_t)(b * 32 + o)) * 256 + X + r) * 256 + y] = vv;
        }
    }
}

// Final MLP: 2 rows per block, 2 pixels per thread
__global__ __launch_bounds__(256) void k_mlp(const float* __restrict__ h,
                                             const float* __restrict__ w0,
                                             const float* __restrict__ b0,
                                             const float* __restrict__ w1,
                                             const float* __restrict__ b1,
                                             float* __restrict__ out) {
    __shared__ float sW0[4096];    // [k][i] broadcast
    __shared__ float sB0[128];
    __shared__ float sW1[384];
    __shared__ float sB1[4];
    int b = blockIdx.x >> 7, X = (blockIdx.x & 127) * 2;
    int y = threadIdx.x;
    for (int idx = y; idx < 4096; idx += 256) {
        int k = idx >> 5, i = idx & 31;
        sW0[idx] = w0[i * 128 + k];
    }
    if (y < 128) sB0[y] = b0[y];
    for (int idx = y; idx < 384; idx += 256) sW1[idx] = w1[idx];
    if (y < 4) sB1[y] = (y < 3) ? b1[y] : 0.f;
    float hreg[2][32];
#pragma unroll
    for (int r = 0; r < 2; ++r)
#pragma unroll
        for (int i = 0; i < 32; ++i)
            hreg[r][i] = h[(((size_t)(b * 32 + i)) * 256 + X + r) * 256 + y];
    __syncthreads();
    float a0[2], a1[2], a2[2];
#pragma unroll
    for (int r = 0; r < 2; ++r) { a0[r] = sB1[0]; a1[r] = sB1[1]; a2[r] = sB1[2]; }
    for (int k = 0; k < 128; ++k) {
        float t[2];
        float bk = sB0[k];
#pragma unroll
        for (int r = 0; r < 2; ++r) t[r] = bk;
#pragma unroll
        for (int i4 = 0; i4 < 8; ++i4) {
            float4 w4 = *reinterpret_cast<const float4*>(sW0 + k * 32 + i4 * 4);
#pragma unroll
            for (int r = 0; r < 2; ++r)
                t[r] += hreg[r][i4 * 4] * w4.x + hreg[r][i4 * 4 + 1] * w4.y
                      + hreg[r][i4 * 4 + 2] * w4.z + hreg[r][i4 * 4 + 3] * w4.w;
        }
        float wa = sW1[k * 3], wb = sW1[k * 3 + 1], wc = sW1[k * 3 + 2];
#pragma unroll
        for (int r = 0; r < 2; ++r) {
            float tg = fgelu(t[r]);
            a0[r] += tg * wa; a1[r] += tg * wb; a2[r] += tg * wc;
        }
    }
#pragma unroll
    for (int r = 0; r < 2; ++r) {
        out[(((size_t)b * 3 + 0) * 256 + X + r) * 256 + y] = a0[r];
        out[(((size_t)b * 3 + 1) * 256 + X + r) * 256 + y] = a1[r];
        out[(((size_t)b * 3 + 2) * 256 + X + r) * 256 + y] = a2[r];
    }
}

extern "C" void kernel_launch(void* const* d_in, const int* in_sizes, int n_in,
                              void* d_out, int out_size, void* d_ws, size_t ws_size,
                              hipStream_t stream) {
    const float* xin  = (const float*)d_in[0];
    const float* pw   = (const float*)d_in[1];
    const float* pb   = (const float*)d_in[2];
    const float* sw1r = (const float*)d_in[3];
    const float* sw1i = (const float*)d_in[4];
    const float* sw2r = (const float*)d_in[5];
    const float* sw2i = (const float*)d_in[6];
    const float* cw   = (const float*)d_in[7];
    const float* cb   = (const float*)d_in[8];
    const float* w0   = (const float*)d_in[9];
    const float* b0   = (const float*)d_in[10];
    const float* w1   = (const float*)d_in[11];
    const float* b1   = (const float*)d_in[12];
    float* out = (float*)d_out;

    float* ws  = (float*)d_ws;
    float* cs  = ws;                  // 512
    float* h   = cs + 512;            // 8388608
    float* tmp = h + 8388608;         // 786432 (aliased with g)
    float* hfp = tmp + 786432;        // 294912 (4 partials)
    float* am  = hfp + 294912;        // 73728
    float* g   = tmp;                 // alias: tmp dead after k_dftx

    k_init<<<1, 256, 0, stream>>>(cs);
    k_lift<<<1024, 256, 0, stream>>>(xin, pw, pb, h);
    for (int l = 0; l < 4; ++l) {
        k_dfty<<<1024, 384, 0, stream>>>(h, tmp);
        k_dftx<<<512, 320, 0, stream>>>(tmp, cs, hfp);
        k_mix<<<96, 384, 0, stream>>>(hfp, sw1r, sw1i, sw2r, sw2i, am, l);
        k_cinv<<<128, 256, 0, stream>>>(am, cs, g);
        k_dinv<<<512, 256, 0, stream>>>(h, g, cw, cb, cs, l, (l < 3) ? 1 : 0);
    }
    k_mlp<<<512, 256, 0, stream>>>(h, w0, b0, w1, b1, out);
}

// Round 4
// 381.412 us; speedup vs baseline: 1.5345x; 1.0865x over previous
//
#include <hip/hip_runtime.h>
#include <math.h>

// FNO2d: B=4, C=3, H=W=256, L=4, WIDTH=32, M1=M2=12
// R4: wave-uniform weights/spectra moved to the SCALAR pipe (s_load) via
// k-major packed weight buffers; k_dinv/k_mlp are 1px/thread, no LDS
// broadcasts, __launch_bounds__(256,4).
//
// ws layout (floats):
//   cs  [512]      : cos/sin(2*pi*p/256)
//   wpk [4612+]    : packed MLP weights [k][32*w0 | b0 | w1*3], +b1 at end
//   cwp [4608]     : packed bypass weights [l][o][32*cw | cb | pad3]
//   h   [8388608]  : activations (B,32,H,W), in place per layer
//   tmp [786432]   : stage-A out (B,32,H,12) complex; ALIASED with g
//   hfp [294912]   : 4 x-partials of (B,32,24,12) complex
//   am  [73728]    : (B,32,24,12) complex after channel mix

#define ANG0 0.024543692606170260f  // 2*pi/256

__device__ __forceinline__ float fgelu(float v) {
    // exact-GELU via A&S 7.1.26 erf approx, |err| <= 1.5e-7, branchless
    float u = v * 0.70710678118f;
    float a = fabsf(u);
    float t = __builtin_amdgcn_rcpf(__builtin_fmaf(0.3275911f, a, 1.0f));
    float p = t * __builtin_fmaf(t, __builtin_fmaf(t, __builtin_fmaf(t,
                  __builtin_fmaf(t, 1.061405429f, -1.453152027f),
                  1.421413741f), -0.284496736f), 0.254829592f);
    float e = __expf(-u * u);
    float er = __builtin_fmaf(-p, e, 1.0f);
    er = copysignf(er, u);
    return 0.5f * v * (1.0f + er);
}

__global__ void k_init(const float* __restrict__ w0, const float* __restrict__ b0,
                       const float* __restrict__ w1, const float* __restrict__ b1,
                       const float* __restrict__ cw, const float* __restrict__ cb,
                       float* __restrict__ cs, float* __restrict__ wpk,
                       float* __restrict__ cwp) {
    int t = threadIdx.x;
    if (blockIdx.x == 0) {
        cs[t]       = cosf(t * ANG0);
        cs[256 + t] = sinf(t * ANG0);
    } else {
        for (int idx = t; idx < 128 * 36; idx += 256) {
            int k = idx / 36, j = idx - k * 36;
            float v;
            if (j < 32)       v = w0[j * 128 + k];
            else if (j == 32) v = b0[k];
            else              v = w1[k * 3 + (j - 33)];
            wpk[idx] = v;
        }
        if (t < 3) wpk[128 * 36 + t] = b1[t];
        for (int idx = t; idx < 4 * 32 * 36; idx += 256) {
            int lo = idx / 36, j = idx - lo * 36;
            int l = lo >> 5, o = lo & 31;
            float v = 0.f;
            if (j < 32)       v = cw[l * 1024 + j * 32 + o];
            else if (j == 32) v = cb[l * 32 + o];
            cwp[idx] = v;
        }
    }
}

__global__ __launch_bounds__(256) void k_lift(const float* __restrict__ xin,
                                              const float* __restrict__ pw,
                                              const float* __restrict__ pb,
                                              float* __restrict__ h) {
    int b = blockIdx.x >> 8, x = blockIdx.x & 255, y = threadIdx.x;
    float f0 = xin[((b * 3 + 0) * 256 + x) * 256 + y];
    float f1 = xin[((b * 3 + 1) * 256 + x) * 256 + y];
    float f2 = xin[((b * 3 + 2) * 256 + x) * 256 + y];
    float gx = x * (1.0f / 255.0f), gy = y * (1.0f / 255.0f);
#pragma unroll
    for (int o = 0; o < 32; ++o) {
        float v = pb[o] + f0 * pw[o] + f1 * pw[32 + o] + f2 * pw[64 + o]
                + gx * pw[96 + o] + gy * pw[128 + o];
        h[((b * 32 + o) * 256 + x) * 256 + y] = v;
    }
}

// Stage A: tmp[row, ky] = sum_y h[row, y] * e^{-2pi i ky y/256}
__global__ __launch_bounds__(384) void k_dfty(const float* __restrict__ h,
                                              float* __restrict__ tmp) {
    __shared__ float sH[32 * 260];
    int tid = threadIdx.x;
    for (int idx = tid; idx < 2048; idx += 384) {
        int r = idx >> 6, yq = idx & 63;
        float4 v = reinterpret_cast<const float4*>(h + ((size_t)blockIdx.x * 32 + r) * 256)[yq];
        *reinterpret_cast<float4*>(&sH[r * 260 + yq * 4]) = v;
    }
    __syncthreads();
    int r = tid / 12, ky = tid % 12;
    float cst = cosf(ky * ANG0), sst = sinf(ky * ANG0);
    float c = 1.f, s = 0.f, aR = 0.f, aI = 0.f;
    const float* hp = sH + r * 260;
#pragma unroll 8
    for (int y = 0; y < 256; ++y) {
        float hv = hp[y];
        aR = __builtin_fmaf(hv, c, aR);
        aI = __builtin_fmaf(hv, s, aI);
        float cn = __builtin_fmaf(c, cst, s * sst);
        s = __builtin_fmaf(s, cst, -c * sst);
        c = cn;
    }
    float2 res = make_float2(aR, aI);
    reinterpret_cast<float2*>(tmp + ((size_t)blockIdx.x * 32 + r) * 24)[ky] = res;
}

// Stage B (4-way x-split): hfp[part][plane][kxi][ky] partial over 64 x's
__global__ __launch_bounds__(320) void k_dftx(const float* __restrict__ tmp,
                                              const float* __restrict__ cs,
                                              float* __restrict__ hfp) {
    __shared__ float sT[1536];
    __shared__ float sCS[512];
    int plane = blockIdx.x >> 2, part = blockIdx.x & 3;
    int x0 = part * 64;
    int tid = threadIdx.x;
    for (int idx = tid; idx < 1536; idx += 320)
        sT[idx] = tmp[(size_t)plane * 6144 + x0 * 24 + idx];
    for (int idx = tid; idx < 512; idx += 320) sCS[idx] = cs[idx];
    __syncthreads();
    if (tid < 288) {
        int kxi = tid / 12, ky = tid % 12;
        int kxv = kxi < 12 ? kxi : 232 + kxi;
        float aR = 0.f, aI = 0.f;
        for (int xp = 0; xp < 64; ++xp) {
            int p = (kxv * (x0 + xp)) & 255;
            float c = sCS[p], s = sCS[256 + p];
            float tr = sT[xp * 24 + 2 * ky], ti = sT[xp * 24 + 2 * ky + 1];
            aR += tr * c + ti * s;
            aI += ti * c - tr * s;
        }
        hfp[(((size_t)part * 128 + plane) * 24 + kxi) * 24 + 2 * ky]     = aR;
        hfp[(((size_t)part * 128 + plane) * 24 + kxi) * 24 + 2 * ky + 1] = aI;
    }
}

// Mode mix (sums the 4 dftx partials while staging)
__global__ __launch_bounds__(384) void k_mix(const float* __restrict__ hfp,
                                             const float* __restrict__ w1r,
                                             const float* __restrict__ w1i,
                                             const float* __restrict__ w2r,
                                             const float* __restrict__ w2i,
                                             float* __restrict__ am, int l) {
    __shared__ float sHF[768];
    int b = blockIdx.x / 24, kxi = blockIdx.x % 24;
    int tid = threadIdx.x;
    for (int idx = tid; idx < 768; idx += 384) {
        int i = idx / 24, rem = idx % 24;
        size_t base = (((size_t)(b * 32 + i)) * 24 + kxi) * 24 + rem;
        sHF[idx] = hfp[base] + hfp[128 * 576 + base] + hfp[2 * 128 * 576 + base]
                 + hfp[3 * 128 * 576 + base];
    }
    __syncthreads();
    int o = tid / 12, ky = tid % 12;
    const float *wr, *wi;
    int rk;
    if (kxi < 12) { wr = w1r; wi = w1i; rk = kxi; }
    else          { wr = w2r; wi = w2i; rk = kxi - 12; }
    size_t base = (size_t)l * 1024 * 144 + rk * 12 + ky;
    float aR = 0.f, aI = 0.f;
#pragma unroll 8
    for (int i = 0; i < 32; ++i) {
        float hr = sHF[i * 24 + 2 * ky], hi = sHF[i * 24 + 2 * ky + 1];
        float wrv = wr[base + (size_t)(i * 32 + o) * 144];
        float wiv = wi[base + (size_t)(i * 32 + o) * 144];
        aR += hr * wrv - hi * wiv;
        aI += hr * wiv + hi * wrv;
    }
    am[(((size_t)b * 32 + o) * 24 + kxi) * 24 + 2 * ky]     = aR;
    am[(((size_t)b * 32 + o) * 24 + kxi) * 24 + 2 * ky + 1] = aI;
}

// Stage C: g[b,o,x,ky] = sum_kx am[b,o,kx,ky] * e^{+2pi i kxv x/256}
__global__ __launch_bounds__(256) void k_cinv(const float* __restrict__ am,
                                              const float* __restrict__ cs,
                                              float* __restrict__ g) {
    __shared__ float sA[576];
    __shared__ float sCS[512];
    int plane = blockIdx.x;
    int tid = threadIdx.x;
    for (int idx = tid; idx < 576; idx += 256) sA[idx] = am[(size_t)plane * 576 + idx];
    for (int idx = tid; idx < 512; idx += 256) sCS[idx] = cs[idx];
    __syncthreads();
    int x = tid;
    float out[24];
#pragma unroll
    for (int j = 0; j < 24; ++j) out[j] = 0.f;
    for (int kxi = 0; kxi < 24; ++kxi) {
        int kxv = kxi < 12 ? kxi : 232 + kxi;
        int p = (kxv * x) & 255;
        float c = sCS[p], s = sCS[256 + p];
#pragma unroll
        for (int ky = 0; ky < 12; ++ky) {
            float ar = sA[kxi * 24 + 2 * ky], ai = sA[kxi * 24 + 2 * ky + 1];
            out[2 * ky]     += ar * c - ai * s;
            out[2 * ky + 1] += ar * s + ai * c;
        }
    }
    float* gp = g + (size_t)plane * 6144 + x * 24;
#pragma unroll
    for (int j = 0; j < 24; ++j) gp[j] = out[j];
}

// Stage D: 1 px/thread; spectra + weights via uniform (scalar) loads.
__global__ __launch_bounds__(256, 4) void k_dinv(float* __restrict__ h,
                                                 const float* __restrict__ g,
                                                 const float* __restrict__ cwp,
                                                 const float* __restrict__ cs,
                                                 int l, int act) {
    __shared__ float sCS[512];
    int b = blockIdx.x >> 8, x = blockIdx.x & 255;
    int y = threadIdx.x;
    for (int idx = y; idx < 512; idx += 256) sCS[idx] = cs[idx];
    float hreg[32];
#pragma unroll
    for (int i = 0; i < 32; ++i)
        hreg[i] = h[(((size_t)(b * 32 + i)) * 256 + x) * 256 + y];
    __syncthreads();
    float ck[12], sk[12];
#pragma unroll
    for (int ky = 1; ky < 12; ++ky) {
        int p = (ky * y) & 255;
        ck[ky] = 2.0f * sCS[p]; sk[ky] = 2.0f * sCS[256 + p];
    }
    const float* gb = g + ((size_t)(b * 32) * 256 + x) * 24;   // per-o stride 6144
    const float* wb = cwp + l * 32 * 36;
    for (int o = 0; o < 32; ++o) {
        const float* gp = gb + (size_t)o * 6144;   // uniform address
        const float* wp = wb + o * 36;             // uniform address
        float spec = gp[0];
#pragma unroll
        for (int ky = 1; ky < 12; ++ky)
            spec += gp[2 * ky] * ck[ky] - gp[2 * ky + 1] * sk[ky];
        float v = __builtin_fmaf(spec, 1.0f / 65536.0f, wp[32]);
#pragma unroll
        for (int i = 0; i < 32; ++i)
            v = __builtin_fmaf(hreg[i], wp[i], v);
        if (act) v = fgelu(v);
        h[(((size_t)(b * 32 + o)) * 256 + x) * 256 + y] = v;
    }
}

// Final MLP: 1 px/thread; packed weights via uniform (scalar) loads, no LDS.
__global__ __launch_bounds__(256, 4) void k_mlp(const float* __restrict__ h,
                                                const float* __restrict__ wpk,
                                                float* __restrict__ out) {
    int b = blockIdx.x >> 8, x = blockIdx.x & 255;
    int y = threadIdx.x;
    float hreg[32];
#pragma unroll
    for (int i = 0; i < 32; ++i)
        hreg[i] = h[(((size_t)(b * 32 + i)) * 256 + x) * 256 + y];
    float a0 = wpk[128 * 36 + 0], a1 = wpk[128 * 36 + 1], a2 = wpk[128 * 36 + 2];
#pragma unroll 2
    for (int k = 0; k < 128; ++k) {
        const float* wp = wpk + k * 36;            // uniform address
        float t = wp[32];
#pragma unroll
        for (int i = 0; i < 32; ++i)
            t = __builtin_fmaf(hreg[i], wp[i], t);
        t = fgelu(t);
        a0 = __builtin_fmaf(t, wp[33], a0);
        a1 = __builtin_fmaf(t, wp[34], a1);
        a2 = __builtin_fmaf(t, wp[35], a2);
    }
    out[(((size_t)b * 3 + 0) * 256 + x) * 256 + y] = a0;
    out[(((size_t)b * 3 + 1) * 256 + x) * 256 + y] = a1;
    out[(((size_t)b * 3 + 2) * 256 + x) * 256 + y] = a2;
}

extern "C" void kernel_launch(void* const* d_in, const int* in_sizes, int n_in,
                              void* d_out, int out_size, void* d_ws, size_t ws_size,
                              hipStream_t stream) {
    const float* xin  = (const float*)d_in[0];
    const float* pw   = (const float*)d_in[1];
    const float* pb   = (const float*)d_in[2];
    const float* sw1r = (const float*)d_in[3];
    const float* sw1i = (const float*)d_in[4];
    const float* sw2r = (const float*)d_in[5];
    const float* sw2i = (const float*)d_in[6];
    const float* cw   = (const float*)d_in[7];
    const float* cb   = (const float*)d_in[8];
    const float* w0   = (const float*)d_in[9];
    const float* b0   = (const float*)d_in[10];
    const float* w1   = (const float*)d_in[11];
    const float* b1   = (const float*)d_in[12];
    float* out = (float*)d_out;

    float* ws  = (float*)d_ws;
    float* cs  = ws;                  // 512
    float* wpk = cs + 512;            // 4624 (128*36 + 3 + pad)
    float* cwp = wpk + 4624;          // 4608
    float* h   = cwp + 4608;          // 8388608
    float* tmp = h + 8388608;         // 786432 (aliased with g)
    float* hfp = tmp + 786432;        // 294912 (4 partials)
    float* am  = hfp + 294912;        // 73728
    float* g   = tmp;                 // alias: tmp dead after k_dftx

    k_init<<<2, 256, 0, stream>>>(w0, b0, w1, b1, cw, cb, cs, wpk, cwp);
    k_lift<<<1024, 256, 0, stream>>>(xin, pw, pb, h);
    for (int l = 0; l < 4; ++l) {
        k_dfty<<<1024, 384, 0, stream>>>(h, tmp);
        k_dftx<<<512, 320, 0, stream>>>(tmp, cs, hfp);
        k_mix<<<96, 384, 0, stream>>>(hfp, sw1r, sw1i, sw2r, sw2i, am, l);
        k_cinv<<<128, 256, 0, stream>>>(am, cs, g);
        k_dinv<<<1024, 256, 0, stream>>>(h, g, cwp, cs, l, (l < 3) ? 1 : 0);
    }
    k_mlp<<<1024, 256, 0, stream>>>(h, wpk, out);
}

// Round 5
// 335.123 us; speedup vs baseline: 1.7464x; 1.1381x over previous
//
#include <hip/hip_runtime.h>
#include <math.h>

// FNO2d: B=4, C=3, H=W=256, L=4, WIDTH=32, M1=M2=12
// R5: kernel-count reduction (23->15) + fusion:
//   k_liftf  = lift + ky-forward-DFT (kills standalone k_dfty)
//   k_dinvf  = bypass+spectral+gelu + next-layer ky-DFT (in-LDS)
//   k_mixcinv= mode-mix + kx-inverse in one kernel (block per (b,o))
//   k_mlp    = 2 px/thread, scalar weights, no LDS
//
// ws layout (floats):
//   wpk [4624]     : packed MLP weights [k][32*w0 | b0 | w1*3], +b1 at end
//   cwp [4608]     : packed bypass weights [l][o][32*cw | cb | pad3]
//   h   [8388608]  : activations (B,32,H,W), in place per layer
//   tmp [786432]   : ky-DFT out (B,32,H,12) complex; ALIASED with g
//   hfp [294912]   : 4 x-partials of (B,32,24,12) complex

#define ANG0 0.024543692606170260f  // 2*pi/256

__device__ __forceinline__ float fgelu(float v) {
    // exact-GELU via A&S 7.1.26 erf approx, |err| <= 1.5e-7, branchless
    float u = v * 0.70710678118f;
    float a = fabsf(u);
    float t = __builtin_amdgcn_rcpf(__builtin_fmaf(0.3275911f, a, 1.0f));
    float p = t * __builtin_fmaf(t, __builtin_fmaf(t, __builtin_fmaf(t,
                  __builtin_fmaf(t, 1.061405429f, -1.453152027f),
                  1.421413741f), -0.284496736f), 0.254829592f);
    float e = __expf(-u * u);
    float er = __builtin_fmaf(-p, e, 1.0f);
    er = copysignf(er, u);
    return 0.5f * v * (1.0f + er);
}

__device__ __forceinline__ void fill_cs(float* sCS, int tid, int nthr) {
    for (int idx = tid; idx < 512; idx += nthr)
        sCS[idx] = (idx < 256) ? cosf(idx * ANG0) : sinf((idx - 256) * ANG0);
}

__global__ void k_init(const float* __restrict__ w0, const float* __restrict__ b0,
                       const float* __restrict__ w1, const float* __restrict__ b1,
                       const float* __restrict__ cw, const float* __restrict__ cb,
                       float* __restrict__ wpk, float* __restrict__ cwp) {
    int t = threadIdx.x;
    for (int idx = t; idx < 128 * 36; idx += 256) {
        int k = idx / 36, j = idx - k * 36;
        float v;
        if (j < 32)       v = w0[j * 128 + k];
        else if (j == 32) v = b0[k];
        else              v = w1[k * 3 + (j - 33)];
        wpk[idx] = v;
    }
    if (t < 3) wpk[128 * 36 + t] = b1[t];
    for (int idx = t; idx < 4 * 32 * 36; idx += 256) {
        int lo = idx / 36, j = idx - lo * 36;
        int l = lo >> 5, o = lo & 31;
        float v = 0.f;
        if (j < 32)       v = cw[l * 1024 + j * 32 + o];
        else if (j == 32) v = cb[l * 32 + o];
        cwp[idx] = v;
    }
}

// Lift + ky-forward DFT for layer 0.
__global__ __launch_bounds__(256, 4) void k_liftf(const float* __restrict__ xin,
                                                  const float* __restrict__ pw,
                                                  const float* __restrict__ pb,
                                                  float* __restrict__ h,
                                                  float* __restrict__ tmp) {
    __shared__ float sV[32 * 257];
    __shared__ float sCS[512];
    int b = blockIdx.x >> 8, x = blockIdx.x & 255, y = threadIdx.x;
    fill_cs(sCS, y, 256);
    float f0 = xin[((b * 3 + 0) * 256 + x) * 256 + y];
    float f1 = xin[((b * 3 + 1) * 256 + x) * 256 + y];
    float f2 = xin[((b * 3 + 2) * 256 + x) * 256 + y];
    float gx = x * (1.0f / 255.0f), gy = y * (1.0f / 255.0f);
#pragma unroll
    for (int o = 0; o < 32; ++o) {
        float v = pb[o] + f0 * pw[o] + f1 * pw[32 + o] + f2 * pw[64 + o]
                + gx * pw[96 + o] + gy * pw[128 + o];
        h[((b * 32 + o) * 256 + x) * 256 + y] = v;
        sV[o * 257 + y] = v;
    }
    __syncthreads();
    for (int idx = y; idx < 384; idx += 256) {
        int o = idx / 12, ky = idx % 12;
        float cst = sCS[ky], sst = sCS[256 + ky];
        float c = 1.f, s = 0.f, aR = 0.f, aI = 0.f;
        const float* vp = sV + o * 257;
#pragma unroll 8
        for (int yy = 0; yy < 256; ++yy) {
            float hv = vp[yy];
            aR = __builtin_fmaf(hv, c, aR);
            aI = __builtin_fmaf(hv, s, aI);
            float cn = __builtin_fmaf(c, cst, s * sst);
            s = __builtin_fmaf(s, cst, -c * sst);
            c = cn;
        }
        reinterpret_cast<float2*>(tmp + (((size_t)(b * 32 + o)) * 256 + x) * 24)[ky] =
            make_float2(aR, aI);
    }
}

// kx-forward DFT (4-way x-split): hfp[part][plane][kxi][ky]
__global__ __launch_bounds__(320) void k_dftx(const float* __restrict__ tmp,
                                              float* __restrict__ hfp) {
    __shared__ float sT[1536];
    __shared__ float sCS[512];
    int plane = blockIdx.x >> 2, part = blockIdx.x & 3;
    int x0 = part * 64;
    int tid = threadIdx.x;
    fill_cs(sCS, tid, 320);
    for (int idx = tid; idx < 1536; idx += 320)
        sT[idx] = tmp[(size_t)plane * 6144 + x0 * 24 + idx];
    __syncthreads();
    if (tid < 288) {
        int kxi = tid / 12, ky = tid % 12;
        int kxv = kxi < 12 ? kxi : 232 + kxi;
        float aR = 0.f, aI = 0.f;
        for (int xp = 0; xp < 64; ++xp) {
            int p = (kxv * (x0 + xp)) & 255;
            float c = sCS[p], s = sCS[256 + p];
            float tr = sT[xp * 24 + 2 * ky], ti = sT[xp * 24 + 2 * ky + 1];
            aR += tr * c + ti * s;
            aI += ti * c - tr * s;
        }
        hfp[(((size_t)part * 128 + plane) * 24 + kxi) * 24 + 2 * ky]     = aR;
        hfp[(((size_t)part * 128 + plane) * 24 + kxi) * 24 + 2 * ky + 1] = aI;
    }
}

// Mode mix + kx-inverse, one block per (b,o).
__global__ __launch_bounds__(320) void k_mixcinv(const float* __restrict__ hfp,
                                                 const float* __restrict__ w1r,
                                                 const float* __restrict__ w1i,
                                                 const float* __restrict__ w2r,
                                                 const float* __restrict__ w2i,
                                                 float* __restrict__ g, int l) {
    __shared__ float sA[576];
    __shared__ float sCS[512];
    int b = blockIdx.x >> 5, o = blockIdx.x & 31;
    int tid = threadIdx.x;
    fill_cs(sCS, tid, 320);
    if (tid < 288) {
        int kxi = tid / 12, ky = tid % 12;
        const float *wr, *wi;
        int rk;
        if (kxi < 12) { wr = w1r; wi = w1i; rk = kxi; }
        else          { wr = w2r; wi = w2i; rk = kxi - 12; }
        size_t wbase = ((size_t)l * 32 * 32) * 144 + (size_t)o * 144 + rk * 12 + ky;
        size_t hbase = (((size_t)(b * 32)) * 24 + kxi) * 24 + 2 * ky;
        float aR = 0.f, aI = 0.f;
#pragma unroll 4
        for (int i = 0; i < 32; ++i) {
            float2 h0 = *reinterpret_cast<const float2*>(hfp + hbase + i * 576);
            float2 h1 = *reinterpret_cast<const float2*>(hfp + 73728 + hbase + i * 576);
            float2 h2 = *reinterpret_cast<const float2*>(hfp + 147456 + hbase + i * 576);
            float2 h3 = *reinterpret_cast<const float2*>(hfp + 221184 + hbase + i * 576);
            float hr = h0.x + h1.x + h2.x + h3.x;
            float hi = h0.y + h1.y + h2.y + h3.y;
            float wrv = wr[wbase + (size_t)i * 4608];
            float wiv = wi[wbase + (size_t)i * 4608];
            aR += hr * wrv - hi * wiv;
            aI += hr * wiv + hi * wrv;
        }
        sA[kxi * 24 + 2 * ky]     = aR;
        sA[kxi * 24 + 2 * ky + 1] = aI;
    }
    __syncthreads();
    if (tid < 256) {
        int x = tid;
        float out[24];
#pragma unroll
        for (int j = 0; j < 24; ++j) out[j] = 0.f;
        for (int kxi = 0; kxi < 24; ++kxi) {
            int kxv = kxi < 12 ? kxi : 232 + kxi;
            int p = (kxv * x) & 255;
            float c = sCS[p], s = sCS[256 + p];
#pragma unroll
            for (int ky = 0; ky < 12; ++ky) {
                float ar = sA[kxi * 24 + 2 * ky], ai = sA[kxi * 24 + 2 * ky + 1];
                out[2 * ky]     += ar * c - ai * s;
                out[2 * ky + 1] += ar * s + ai * c;
            }
        }
        float* gp = g + ((size_t)(b * 32 + o)) * 6144 + x * 24;
#pragma unroll
        for (int j = 0; j < 24; ++j) gp[j] = out[j];
    }
}

// Stage D + next-layer ky-DFT. 1 px/thread, scalar g/weight loads.
// g aliases tmp: g is read (scalar) before the barrier, tmp written after;
// each block touches only its own x-slice -> race-free.
__global__ __launch_bounds__(256, 4) void k_dinvf(float* __restrict__ h,
                                                  const float* __restrict__ g,
                                                  const float* __restrict__ cwp,
                                                  float* __restrict__ tmp,
                                                  int l, int act, int dodft) {
    __shared__ float sV[32 * 257];
    __shared__ float sCS[512];
    int b = blockIdx.x >> 8, x = blockIdx.x & 255;
    int y = threadIdx.x;
    fill_cs(sCS, y, 256);
    float hreg[32];
#pragma unroll
    for (int i = 0; i < 32; ++i)
        hreg[i] = h[(((size_t)(b * 32 + i)) * 256 + x) * 256 + y];
    __syncthreads();
    float ck[12], sk[12];
#pragma unroll
    for (int ky = 1; ky < 12; ++ky) {
        int p = (ky * y) & 255;
        ck[ky] = 2.0f * sCS[p]; sk[ky] = 2.0f * sCS[256 + p];
    }
    const float* gb = g + ((size_t)(b * 32) * 256 + x) * 24;
    const float* wb = cwp + l * 32 * 36;
    for (int o = 0; o < 32; ++o) {
        const float* gp = gb + (size_t)o * 6144;   // uniform address
        const float* wp = wb + o * 36;             // uniform address
        float spec = gp[0];
#pragma unroll
        for (int ky = 1; ky < 12; ++ky)
            spec += gp[2 * ky] * ck[ky] - gp[2 * ky + 1] * sk[ky];
        float v = __builtin_fmaf(spec, 1.0f / 65536.0f, wp[32]);
#pragma unroll
        for (int i = 0; i < 32; ++i)
            v = __builtin_fmaf(hreg[i], wp[i], v);
        if (act) v = fgelu(v);
        h[(((size_t)(b * 32 + o)) * 256 + x) * 256 + y] = v;
        if (dodft) sV[o * 257 + y] = v;
    }
    if (dodft) {
        __syncthreads();
        for (int idx = y; idx < 384; idx += 256) {
            int o = idx / 12, ky = idx % 12;
            float cst = sCS[ky], sst = sCS[256 + ky];
            float c = 1.f, s = 0.f, aR = 0.f, aI = 0.f;
            const float* vp = sV + o * 257;
#pragma unroll 8
            for (int yy = 0; yy < 256; ++yy) {
                float hv = vp[yy];
                aR = __builtin_fmaf(hv, c, aR);
                aI = __builtin_fmaf(hv, s, aI);
                float cn = __builtin_fmaf(c, cst, s * sst);
                s = __builtin_fmaf(s, cst, -c * sst);
                c = cn;
            }
            reinterpret_cast<float2*>(tmp + (((size_t)(b * 32 + o)) * 256 + x) * 24)[ky] =
                make_float2(aR, aI);
        }
    }
}

// Final MLP: 2 px/thread (rows X, X+1), scalar packed weights, no LDS.
__global__ __launch_bounds__(256, 2) void k_mlp(const float* __restrict__ h,
                                                const float* __restrict__ wpk,
                                                float* __restrict__ out) {
    int b = blockIdx.x >> 7, X = (blockIdx.x & 127) * 2;
    int y = threadIdx.x;
    float hreg[2][32];
#pragma unroll
    for (int r = 0; r < 2; ++r)
#pragma unroll
        for (int i = 0; i < 32; ++i)
            hreg[r][i] = h[(((size_t)(b * 32 + i)) * 256 + X + r) * 256 + y];
    float a0[2], a1[2], a2[2];
#pragma unroll
    for (int r = 0; r < 2; ++r) {
        a0[r] = wpk[128 * 36 + 0]; a1[r] = wpk[128 * 36 + 1]; a2[r] = wpk[128 * 36 + 2];
    }
#pragma unroll 2
    for (int k = 0; k < 128; ++k) {
        const float* wp = wpk + k * 36;            // uniform address
        float t0 = wp[32], t1 = wp[32];
#pragma unroll
        for (int i = 0; i < 32; ++i) {
            float w = wp[i];
            t0 = __builtin_fmaf(hreg[0][i], w, t0);
            t1 = __builtin_fmaf(hreg[1][i], w, t1);
        }
        t0 = fgelu(t0); t1 = fgelu(t1);
        float wa = wp[33], wb = wp[34], wc = wp[35];
        a0[0] = __builtin_fmaf(t0, wa, a0[0]); a0[1] = __builtin_fmaf(t1, wa, a0[1]);
        a1[0] = __builtin_fmaf(t0, wb, a1[0]); a1[1] = __builtin_fmaf(t1, wb, a1[1]);
        a2[0] = __builtin_fmaf(t0, wc, a2[0]); a2[1] = __builtin_fmaf(t1, wc, a2[1]);
    }
#pragma unroll
    for (int r = 0; r < 2; ++r) {
        out[(((size_t)b * 3 + 0) * 256 + X + r) * 256 + y] = a0[r];
        out[(((size_t)b * 3 + 1) * 256 + X + r) * 256 + y] = a1[r];
        out[(((size_t)b * 3 + 2) * 256 + X + r) * 256 + y] = a2[r];
    }
}

extern "C" void kernel_launch(void* const* d_in, const int* in_sizes, int n_in,
                              void* d_out, int out_size, void* d_ws, size_t ws_size,
                              hipStream_t stream) {
    const float* xin  = (const float*)d_in[0];
    const float* pw   = (const float*)d_in[1];
    const float* pb   = (const float*)d_in[2];
    const float* sw1r = (const float*)d_in[3];
    const float* sw1i = (const float*)d_in[4];
    const float* sw2r = (const float*)d_in[5];
    const float* sw2i = (const float*)d_in[6];
    const float* cw   = (const float*)d_in[7];
    const float* cb   = (const float*)d_in[8];
    const float* w0   = (const float*)d_in[9];
    const float* b0   = (const float*)d_in[10];
    const float* w1   = (const float*)d_in[11];
    const float* b1   = (const float*)d_in[12];
    float* out = (float*)d_out;

    float* ws  = (float*)d_ws;
    float* wpk = ws;                  // 4624
    float* cwp = wpk + 4624;          // 4608
    float* h   = cwp + 4608;          // 8388608
    float* tmp = h + 8388608;         // 786432 (aliased with g)
    float* hfp = tmp + 786432;        // 294912
    float* g   = tmp;                 // alias

    k_init<<<1, 256, 0, stream>>>(w0, b0, w1, b1, cw, cb, wpk, cwp);
    k_liftf<<<1024, 256, 0, stream>>>(xin, pw, pb, h, tmp);
    for (int l = 0; l < 4; ++l) {
        k_dftx<<<512, 320, 0, stream>>>(tmp, hfp);
        k_mixcinv<<<128, 320, 0, stream>>>(hfp, sw1r, sw1i, sw2r, sw2i, g, l);
        k_dinvf<<<1024, 256, 0, stream>>>(h, g, cwp, tmp, l,
                                          (l < 3) ? 1 : 0, (l < 3) ? 1 : 0);
    }
    k_mlp<<<512, 256, 0, stream>>>(h, wpk, out);
}

// Round 6
// 307.553 us; speedup vs baseline: 1.9030x; 1.0896x over previous
//
#include <hip/hip_runtime.h>
#include <math.h>

// FNO2d: B=4, C=3, H=W=256, L=4, WIDTH=32, M1=M2=12
// R6: symmetric-pair ky-DFT tails (no serial rotation), float2 cs tables,
// l=3 layer fused with the final MLP (k_dinvmlp) -> h round-trip removed.
//
// ws layout (floats):
//   wpk [4624]     : packed MLP weights [k][32*w0 | b0 | w1*3], +b1 at end
//   cwp [4608]     : packed bypass weights [l][o][32*cw | cb | pad3]
//   h   [8388608]  : activations (B,32,H,W), in place per layer
//   tmp [786432]   : ky-DFT out (B,32,H,12) complex; ALIASED with g
//   hfp [294912]   : 4 x-partials of (B,32,24,12) complex

#define ANG0 0.024543692606170260f  // 2*pi/256

__device__ __forceinline__ float fgelu(float v) {
    // exact-GELU via A&S 7.1.26 erf approx, |err| <= 1.5e-7, branchless
    float u = v * 0.70710678118f;
    float a = fabsf(u);
    float t = __builtin_amdgcn_rcpf(__builtin_fmaf(0.3275911f, a, 1.0f));
    float p = t * __builtin_fmaf(t, __builtin_fmaf(t, __builtin_fmaf(t,
                  __builtin_fmaf(t, 1.061405429f, -1.453152027f),
                  1.421413741f), -0.284496736f), 0.254829592f);
    float e = __expf(-u * u);
    float er = __builtin_fmaf(-p, e, 1.0f);
    er = copysignf(er, u);
    return 0.5f * v * (1.0f + er);
}

__device__ __forceinline__ void fill_csp(float2* sCSP, int tid, int nthr) {
    for (int p = tid; p < 256; p += nthr)
        sCSP[p] = make_float2(cosf(p * ANG0), sinf(p * ANG0));
}

// ky-forward DFT over one (b,x) column held in sV[o*257 + y], symmetric pairs.
__device__ __forceinline__ void ky_dft_tail(const float* sV, const float2* sCSP,
                                            float* tmp, int b, int x, int y) {
    for (int idx = y; idx < 384; idx += 256) {
        int o = idx / 12, ky = idx % 12;
        const float* vp = sV + o * 257;
        float v128 = vp[128];
        float aR = vp[0] + ((ky & 1) ? -v128 : v128);
        float aI = 0.f;
#pragma unroll 4
        for (int yy = 1; yy <= 127; ++yy) {
            int p = (ky * yy) & 255;
            float2 cs2 = sCSP[p];
            float fw = vp[yy], bw = vp[256 - yy];
            float e = fw + bw, d = fw - bw;
            aR = __builtin_fmaf(e, cs2.x, aR);
            aI = __builtin_fmaf(d, -cs2.y, aI);
        }
        reinterpret_cast<float2*>(tmp + (((size_t)(b * 32 + o)) * 256 + x) * 24)[ky] =
            make_float2(aR, aI);
    }
}

__global__ void k_init(const float* __restrict__ w0, const float* __restrict__ b0,
                       const float* __restrict__ w1, const float* __restrict__ b1,
                       const float* __restrict__ cw, const float* __restrict__ cb,
                       float* __restrict__ wpk, float* __restrict__ cwp) {
    int t = threadIdx.x;
    for (int idx = t; idx < 128 * 36; idx += 256) {
        int k = idx / 36, j = idx - k * 36;
        float v;
        if (j < 32)       v = w0[j * 128 + k];
        else if (j == 32) v = b0[k];
        else              v = w1[k * 3 + (j - 33)];
        wpk[idx] = v;
    }
    if (t < 3) wpk[128 * 36 + t] = b1[t];
    for (int idx = t; idx < 4 * 32 * 36; idx += 256) {
        int lo = idx / 36, j = idx - lo * 36;
        int l = lo >> 5, o = lo & 31;
        float v = 0.f;
        if (j < 32)       v = cw[l * 1024 + j * 32 + o];
        else if (j == 32) v = cb[l * 32 + o];
        cwp[idx] = v;
    }
}

// Lift + ky-forward DFT for layer 0.
__global__ __launch_bounds__(256, 4) void k_liftf(const float* __restrict__ xin,
                                                  const float* __restrict__ pw,
                                                  const float* __restrict__ pb,
                                                  float* __restrict__ h,
                                                  float* __restrict__ tmp) {
    __shared__ float sV[32 * 257];
    __shared__ float2 sCSP[256];
    int b = blockIdx.x >> 8, x = blockIdx.x & 255, y = threadIdx.x;
    fill_csp(sCSP, y, 256);
    float f0 = xin[((b * 3 + 0) * 256 + x) * 256 + y];
    float f1 = xin[((b * 3 + 1) * 256 + x) * 256 + y];
    float f2 = xin[((b * 3 + 2) * 256 + x) * 256 + y];
    float gx = x * (1.0f / 255.0f), gy = y * (1.0f / 255.0f);
#pragma unroll
    for (int o = 0; o < 32; ++o) {
        float v = pb[o] + f0 * pw[o] + f1 * pw[32 + o] + f2 * pw[64 + o]
                + gx * pw[96 + o] + gy * pw[128 + o];
        h[((b * 32 + o) * 256 + x) * 256 + y] = v;
        sV[o * 257 + y] = v;
    }
    __syncthreads();
    ky_dft_tail(sV, sCSP, tmp, b, x, y);
}

// kx-forward DFT (4-way x-split): hfp[part][plane][kxi][ky]
__global__ __launch_bounds__(320) void k_dftx(const float* __restrict__ tmp,
                                              float* __restrict__ hfp) {
    __shared__ float sT[1536];
    __shared__ float2 sCSP[256];
    int plane = blockIdx.x >> 2, part = blockIdx.x & 3;
    int x0 = part * 64;
    int tid = threadIdx.x;
    fill_csp(sCSP, tid, 320);
    for (int idx = tid; idx < 1536; idx += 320)
        sT[idx] = tmp[(size_t)plane * 6144 + x0 * 24 + idx];
    __syncthreads();
    if (tid < 288) {
        int kxi = tid / 12, ky = tid % 12;
        int kxv = kxi < 12 ? kxi : 232 + kxi;
        float aR = 0.f, aI = 0.f;
        for (int xp = 0; xp < 64; ++xp) {
            int p = (kxv * (x0 + xp)) & 255;
            float2 cs2 = sCSP[p];
            float tr = sT[xp * 24 + 2 * ky], ti = sT[xp * 24 + 2 * ky + 1];
            aR += tr * cs2.x + ti * cs2.y;
            aI += ti * cs2.x - tr * cs2.y;
        }
        hfp[(((size_t)part * 128 + plane) * 24 + kxi) * 24 + 2 * ky]     = aR;
        hfp[(((size_t)part * 128 + plane) * 24 + kxi) * 24 + 2 * ky + 1] = aI;
    }
}

// Mode mix + kx-inverse, one block per (b,o).
__global__ __launch_bounds__(320) void k_mixcinv(const float* __restrict__ hfp,
                                                 const float* __restrict__ w1r,
                                                 const float* __restrict__ w1i,
                                                 const float* __restrict__ w2r,
                                                 const float* __restrict__ w2i,
                                                 float* __restrict__ g, int l) {
    __shared__ float sA[576];
    __shared__ float2 sCSP[256];
    int b = blockIdx.x >> 5, o = blockIdx.x & 31;
    int tid = threadIdx.x;
    fill_csp(sCSP, tid, 320);
    if (tid < 288) {
        int kxi = tid / 12, ky = tid % 12;
        const float *wr, *wi;
        int rk;
        if (kxi < 12) { wr = w1r; wi = w1i; rk = kxi; }
        else          { wr = w2r; wi = w2i; rk = kxi - 12; }
        size_t wbase = ((size_t)l * 32 * 32) * 144 + (size_t)o * 144 + rk * 12 + ky;
        size_t hbase = (((size_t)(b * 32)) * 24 + kxi) * 24 + 2 * ky;
        float aR = 0.f, aI = 0.f;
#pragma unroll 4
        for (int i = 0; i < 32; ++i) {
            float2 h0 = *reinterpret_cast<const float2*>(hfp + hbase + i * 576);
            float2 h1 = *reinterpret_cast<const float2*>(hfp + 73728 + hbase + i * 576);
            float2 h2 = *reinterpret_cast<const float2*>(hfp + 147456 + hbase + i * 576);
            float2 h3 = *reinterpret_cast<const float2*>(hfp + 221184 + hbase + i * 576);
            float hr = h0.x + h1.x + h2.x + h3.x;
            float hi = h0.y + h1.y + h2.y + h3.y;
            float wrv = wr[wbase + (size_t)i * 4608];
            float wiv = wi[wbase + (size_t)i * 4608];
            aR += hr * wrv - hi * wiv;
            aI += hr * wiv + hi * wrv;
        }
        sA[kxi * 24 + 2 * ky]     = aR;
        sA[kxi * 24 + 2 * ky + 1] = aI;
    }
    __syncthreads();
    if (tid < 256) {
        int x = tid;
        float out[24];
#pragma unroll
        for (int j = 0; j < 24; ++j) out[j] = 0.f;
        for (int kxi = 0; kxi < 24; ++kxi) {
            int kxv = kxi < 12 ? kxi : 232 + kxi;
            int p = (kxv * x) & 255;
            float2 cs2 = sCSP[p];
#pragma unroll
            for (int ky = 0; ky < 12; ++ky) {
                float ar = sA[kxi * 24 + 2 * ky], ai = sA[kxi * 24 + 2 * ky + 1];
                out[2 * ky]     += ar * cs2.x - ai * cs2.y;
                out[2 * ky + 1] += ar * cs2.y + ai * cs2.x;
            }
        }
        float* gp = g + ((size_t)(b * 32 + o)) * 6144 + x * 24;
#pragma unroll
        for (int j = 0; j < 24; ++j) gp[j] = out[j];
    }
}

// Layers 0..2: bypass+spectral+gelu, in-place h, + next-layer ky-DFT.
// g aliases tmp: all g reads precede the barrier; tail writes after.
__global__ __launch_bounds__(256, 4) void k_dinvf(float* __restrict__ h,
                                                  const float* __restrict__ g,
                                                  const float* __restrict__ cwp,
                                                  float* __restrict__ tmp,
                                                  int l) {
    __shared__ float sV[32 * 257];
    __shared__ float2 sCSP[256];
    int b = blockIdx.x >> 8, x = blockIdx.x & 255;
    int y = threadIdx.x;
    fill_csp(sCSP, y, 256);
    float hreg[32];
#pragma unroll
    for (int i = 0; i < 32; ++i)
        hreg[i] = h[(((size_t)(b * 32 + i)) * 256 + x) * 256 + y];
    __syncthreads();
    float ck[12], sk[12];
#pragma unroll
    for (int ky = 1; ky < 12; ++ky) {
        int p = (ky * y) & 255;
        float2 cs2 = sCSP[p];
        ck[ky] = 2.0f * cs2.x; sk[ky] = 2.0f * cs2.y;
    }
    const float* gb = g + ((size_t)(b * 32) * 256 + x) * 24;
    const float* wb = cwp + l * 32 * 36;
    for (int o = 0; o < 32; ++o) {
        const float* gp = gb + (size_t)o * 6144;   // uniform address
        const float* wp = wb + o * 36;             // uniform address
        float spec = gp[0];
#pragma unroll
        for (int ky = 1; ky < 12; ++ky)
            spec += gp[2 * ky] * ck[ky] - gp[2 * ky + 1] * sk[ky];
        float v = __builtin_fmaf(spec, 1.0f / 65536.0f, wp[32]);
#pragma unroll
        for (int i = 0; i < 32; ++i)
            v = __builtin_fmaf(hreg[i], wp[i], v);
        v = fgelu(v);
        h[(((size_t)(b * 32 + o)) * 256 + x) * 256 + y] = v;
        sV[o * 257 + y] = v;
    }
    __syncthreads();
    ky_dft_tail(sV, sCSP, tmp, b, x, y);
}

// Layer 3 (no gelu, no DFT) fused with the final MLP; h never written.
__global__ __launch_bounds__(256, 4) void k_dinvmlp(const float* __restrict__ h,
                                                    const float* __restrict__ g,
                                                    const float* __restrict__ cwp,
                                                    const float* __restrict__ wpk,
                                                    float* __restrict__ out) {
    __shared__ float2 sCSP[256];
    int b = blockIdx.x >> 8, x = blockIdx.x & 255;
    int y = threadIdx.x;
    fill_csp(sCSP, y, 256);
    float hreg[32];
#pragma unroll
    for (int i = 0; i < 32; ++i)
        hreg[i] = h[(((size_t)(b * 32 + i)) * 256 + x) * 256 + y];
    __syncthreads();
    float ck[12], sk[12];
#pragma unroll
    for (int ky = 1; ky < 12; ++ky) {
        int p = (ky * y) & 255;
        float2 cs2 = sCSP[p];
        ck[ky] = 2.0f * cs2.x; sk[ky] = 2.0f * cs2.y;
    }
    const float* gb = g + ((size_t)(b * 32) * 256 + x) * 24;
    const float* wb = cwp + 3 * 32 * 36;
    float v[32];
#pragma unroll
    for (int o = 0; o < 32; ++o) {
        const float* gp = gb + (size_t)o * 6144;   // uniform address
        const float* wp = wb + o * 36;             // uniform address
        float spec = gp[0];
#pragma unroll
        for (int ky = 1; ky < 12; ++ky)
            spec += gp[2 * ky] * ck[ky] - gp[2 * ky + 1] * sk[ky];
        float t = __builtin_fmaf(spec, 1.0f / 65536.0f, wp[32]);
#pragma unroll
        for (int i = 0; i < 32; ++i)
            t = __builtin_fmaf(hreg[i], wp[i], t);
        v[o] = t;
    }
    float a0 = wpk[128 * 36 + 0], a1 = wpk[128 * 36 + 1], a2 = wpk[128 * 36 + 2];
#pragma unroll 2
    for (int k = 0; k < 128; ++k) {
        const float* wp = wpk + k * 36;            // uniform address
        float t = wp[32];
#pragma unroll
        for (int i = 0; i < 32; ++i)
            t = __builtin_fmaf(v[i], wp[i], t);
        t = fgelu(t);
        a0 = __builtin_fmaf(t, wp[33], a0);
        a1 = __builtin_fmaf(t, wp[34], a1);
        a2 = __builtin_fmaf(t, wp[35], a2);
    }
    out[(((size_t)b * 3 + 0) * 256 + x) * 256 + y] = a0;
    out[(((size_t)b * 3 + 1) * 256 + x) * 256 + y] = a1;
    out[(((size_t)b * 3 + 2) * 256 + x) * 256 + y] = a2;
}

extern "C" void kernel_launch(void* const* d_in, const int* in_sizes, int n_in,
                              void* d_out, int out_size, void* d_ws, size_t ws_size,
                              hipStream_t stream) {
    const float* xin  = (const float*)d_in[0];
    const float* pw   = (const float*)d_in[1];
    const float* pb   = (const float*)d_in[2];
    const float* sw1r = (const float*)d_in[3];
    const float* sw1i = (const float*)d_in[4];
    const float* sw2r = (const float*)d_in[5];
    const float* sw2i = (const float*)d_in[6];
    const float* cw   = (const float*)d_in[7];
    const float* cb   = (const float*)d_in[8];
    const float* w0   = (const float*)d_in[9];
    const float* b0   = (const float*)d_in[10];
    const float* w1   = (const float*)d_in[11];
    const float* b1   = (const float*)d_in[12];
    float* out = (float*)d_out;

    float* ws  = (float*)d_ws;
    float* wpk = ws;                  // 4624
    float* cwp = wpk + 4624;          // 4608
    float* h   = cwp + 4608;          // 8388608
    float* tmp = h + 8388608;         // 786432 (aliased with g)
    float* hfp = tmp + 786432;        // 294912
    float* g   = tmp;                 // alias

    k_init<<<1, 256, 0, stream>>>(w0, b0, w1, b1, cw, cb, wpk, cwp);
    k_liftf<<<1024, 256, 0, stream>>>(xin, pw, pb, h, tmp);
    for (int l = 0; l < 4; ++l) {
        k_dftx<<<512, 320, 0, stream>>>(tmp, hfp);
        k_mixcinv<<<128, 320, 0, stream>>>(hfp, sw1r, sw1i, sw2r, sw2i, g, l);
        if (l < 3)
            k_dinvf<<<1024, 256, 0, stream>>>(h, g, cwp, tmp, l);
        else
            k_dinvmlp<<<1024, 256, 0, stream>>>(h, g, cwp, wpk, out);
    }
}